// Round 3
// baseline (76.408 us; speedup 1.0000x reference)
//
#include <hip/hip_runtime.h>

#define NPTS 4096
#define NB   8

typedef __attribute__((ext_vector_type(8)))  short          bf16x8;
typedef __attribute__((ext_vector_type(8)))  unsigned short u16x8;
typedef __attribute__((ext_vector_type(16))) float          f32x16;

__device__ __forceinline__ unsigned short bf16_rne(float f) {
    unsigned u = __float_as_uint(f);
    u += 0x7FFFu + ((u >> 16) & 1u);
    return (unsigned short)(u >> 16);
}
__device__ __forceinline__ float bf16_f(unsigned short s) {
    return __uint_as_float(((unsigned)s) << 16);
}

// s(i,j) = ah.bh(3) + al.bh(3) + ah.bl(3) + 1*hh + 1*hl   (11 K-slots of 16)
// A slots: [ah0,ah1,ah2, al0,al1,al2, ah0,ah1 | ah2, 1, 1, 0,0,0,0,0]
// B slots: [bh0,bh1,bh2, bh0,bh1,bh2, bl0,bl1 | bl2, hh, hl, 0,0,0,0,0]
// 32x32x16 operand layout: lane l -> point (32u + (l&31)), k-slots 8*(l>>5)..+7.
// MFMA core math + C/D map verified R7..R16; R21 fused-LDS variant verified
// on HW (absmax 0.0, 66.49us).
// R22: full-j blocks — grid 256 = 16 clouds x 16 i-halves, whole B cloud in
//      128KB dynamic LDS (same byte layout, u=0..127), 2 i-tiles/wave.
//      Row-max is final in-block -> fold h_a, block-sum -> 1 float/block.
//      Kernel 2 = single block summing 256 floats (plain store, no atomics,
//      no out-zeroing). Removes 1MB smaxp round-trip + reduce's x/y re-read.

// ---------------- pass 0: MFMA chamfer core, full j per block ----------------
__global__ __launch_bounds__(256, 1) void chamfer_fused(
    const float* __restrict__ x, const float* __restrict__ y,
    float* __restrict__ partials)
{
    extern __shared__ char smem[];                       // 128 KB dynamic
    unsigned short* sB = (unsigned short*)smem;          // B fragments
    float (*buf)[64][33] = (float (*)[64][33])smem;      // aliased after barrier
    __shared__ float redb[4];

    const int bid  = blockIdx.x;
    const int dirb = bid >> 4;        // 0..15 (A-cloud id)
    const int ib2  = bid & 15;        // 0..15 (256-row i-slab)

    const int tid = threadIdx.x;
    const int w   = tid >> 6;         // wave 0..3
    const int l   = tid & 63;
    const int g   = l >> 5;           // k-half
    const int pos = l & 31;           // row/col within tile

    const float* Araw = (dirb < 8) ? x + (size_t)dirb * NPTS * 3
                                   : y + (size_t)(dirb - 8) * NPTS * 3;
    const int bcid = dirb ^ 8;
    const float* Braw = (bcid < 8) ? x + (size_t)bcid * NPTS * 3
                                   : y + (size_t)(bcid - 8) * NPTS * 3;

    // ---- convert the whole B cloud (4096 points) into LDS ----
    // byte layout: u*1024 + ppos*16 (+512 for hi half), u = 0..127
    #pragma unroll
    for (int k = 0; k < 16; ++k) {
        int p = k * 256 + tid;                       // 0..4095
        const float* src = Braw + (size_t)p * 3;
        float c0 = src[0], c1 = src[1], c2 = src[2];
        float h  = -0.5f * (c0 * c0 + c1 * c1 + c2 * c2);
        unsigned short h0 = bf16_rne(c0), h1 = bf16_rne(c1), h2 = bf16_rne(c2);
        unsigned short l0 = bf16_rne(c0 - bf16_f(h0));
        unsigned short l1 = bf16_rne(c1 - bf16_f(h1));
        unsigned short l2 = bf16_rne(c2 - bf16_f(h2));
        unsigned short hh = bf16_rne(h);
        unsigned short hl = bf16_rne(h - bf16_f(hh));
        u16x8 blo, bhi;
        blo[0]=h0; blo[1]=h1; blo[2]=h2; blo[3]=h0; blo[4]=h1; blo[5]=h2; blo[6]=l0; blo[7]=l1;
        bhi[0]=l2; bhi[1]=hh; bhi[2]=hl; bhi[3]=0; bhi[4]=0; bhi[5]=0; bhi[6]=0; bhi[7]=0;
        int u = p >> 5, ppos = p & 31;
        char* dst = (char*)sB + (size_t)u * 1024 + (size_t)ppos * 16;
        *(u16x8*)dst         = blo;
        *(u16x8*)(dst + 512) = bhi;
    }

    // ---- A fragments in-register from raw floats (verified recipe) ----
    const int it0 = ib2 * 8 + w * 2;      // 2 i-tiles per wave
    bf16x8 afr[2];
    #pragma unroll
    for (int t = 0; t < 2; ++t) {
        const float* ap = Araw + (size_t)((it0 + t) * 32 + pos) * 3;
        float c0 = ap[0], c1 = ap[1], c2 = ap[2];
        unsigned short h0 = bf16_rne(c0), h1 = bf16_rne(c1), h2 = bf16_rne(c2);
        unsigned short l0 = bf16_rne(c0 - bf16_f(h0));
        unsigned short l1 = bf16_rne(c1 - bf16_f(h1));
        unsigned short l2 = bf16_rne(c2 - bf16_f(h2));
        const short ONE = (short)0x3F80;
        bf16x8 alo, ahi;
        alo[0]=(short)h0; alo[1]=(short)h1; alo[2]=(short)h2; alo[3]=(short)l0;
        alo[4]=(short)l1; alo[5]=(short)l2; alo[6]=(short)h0; alo[7]=(short)h1;
        ahi[0]=(short)h2; ahi[1]=ONE; ahi[2]=ONE; ahi[3]=0;
        ahi[4]=0; ahi[5]=0; ahi[6]=0; ahi[7]=0;
        #pragma unroll
        for (int e = 0; e < 8; ++e) afr[t][e] = g ? ahi[e] : alo[e];
    }

    __syncthreads();   // LDS B tile ready

    f32x16 zc;
    #pragma unroll
    for (int r = 0; r < 16; ++r) zc[r] = 0.f;

    f32x16 run[2];
    #pragma unroll
    for (int t = 0; t < 2; ++t)
        #pragma unroll
        for (int r = 0; r < 16; ++r) run[t][r] = -3.0e38f;

    // pipeline registers (dummy-init; first consume folds -3e38 into run[1])
    f32x16 p0, p1;
    #pragma unroll
    for (int r = 0; r < 16; ++r) { p0[r] = -3.0e38f; p1[r] = -3.0e38f; }

    const char* Bq = (const char*)sB + (size_t)g * 512 + (size_t)pos * 16;

    bf16x8 cb0 = *(const bf16x8*)(Bq);
    bf16x8 cb1 = *(const bf16x8*)(Bq + 1024);
    bf16x8 cb2 = *(const bf16x8*)(Bq + 2048);
    bf16x8 cb3 = *(const bf16x8*)(Bq + 3072);

#define STAGE(T, B0, B1, RP)                                                    \
    {                                                                           \
        f32x16 d0 = __builtin_amdgcn_mfma_f32_32x32x16_bf16(afr[T], B0, zc, 0, 0, 0); \
        f32x16 d1 = __builtin_amdgcn_mfma_f32_32x32x16_bf16(afr[T], B1, zc, 0, 0, 0); \
        _Pragma("unroll")                                                       \
        for (int r = 0; r < 16; ++r)                                            \
            run[RP][r] = fmaxf(fmaxf(p0[r], p1[r]), run[RP][r]);                \
        p0 = d0; p1 = d1;                                                       \
    }

    #pragma unroll 1
    for (int j = 0; j < 128; j += 4) {
        bf16x8 nb0, nb1, nb2, nb3;
        if (j < 124) {                      // wave-uniform scalar branch
            const char* Bn = Bq + (size_t)(j + 4) * 1024;
            nb0 = *(const bf16x8*)(Bn);
            nb1 = *(const bf16x8*)(Bn + 1024);
            nb2 = *(const bf16x8*)(Bn + 2048);
            nb3 = *(const bf16x8*)(Bn + 3072);
        }
        // RP = tile of the PREVIOUS stage: sequence T=0,1,0,1 -> RP=1,0,1,0
        STAGE(0, cb0, cb1, 1)
        STAGE(1, cb0, cb1, 0)
        STAGE(0, cb2, cb3, 1)
        STAGE(1, cb2, cb3, 0)
        if (j < 124) { cb0 = nb0; cb1 = nb1; cb2 = nb2; cb3 = nb3; }
    }
#undef STAGE

    // drain: last stage used afr[1]
    #pragma unroll
    for (int r = 0; r < 16; ++r)
        run[1][r] = fmaxf(fmaxf(p0[r], p1[r]), run[1][r]);

    __syncthreads();   // all B reads complete -> safe to alias smem as buf

    // ---- epilogue: single phase, 2 i-tiles -> 64 rows per wave ----
    #pragma unroll
    for (int tl = 0; tl < 2; ++tl) {
        #pragma unroll
        for (int r = 0; r < 16; ++r) {
            int rowin = (r & 3) + 8 * (r >> 2) + 4 * g;   // verified C/D map
            buf[w][tl * 32 + rowin][pos] = run[tl][r];
        }
    }
    __syncthreads();

    float m = buf[w][l][0];
    #pragma unroll
    for (int k = 1; k < 32; ++k) m = fmaxf(m, buf[w][l][k]);

    // fold h_a = -0.5*|a|^2 for this lane's row, then block-sum
    int row = ib2 * 256 + w * 64 + l;
    const float* ap = Araw + (size_t)row * 3;
    float a0 = ap[0], a1 = ap[1], a2 = ap[2];
    float s = m - 0.5f * (a0 * a0 + a1 * a1 + a2 * a2);

    #pragma unroll
    for (int off = 32; off > 0; off >>= 1)
        s += __shfl_down(s, off);

    if (l == 0) redb[w] = s;
    __syncthreads();
    if (tid == 0)
        partials[bid] = redb[0] + redb[1] + redb[2] + redb[3];
}

// ---------------- pass 1: sum 256 partials, scale, store ----------------
__global__ __launch_bounds__(256) void final_reduce(
    const float* __restrict__ partials, float* __restrict__ out)
{
    float s = partials[threadIdx.x];
    #pragma unroll
    for (int off = 32; off > 0; off >>= 1)
        s += __shfl_down(s, off);

    __shared__ float redb[4];
    const int lane = threadIdx.x & 63, wave = threadIdx.x >> 6;
    if (lane == 0) redb[wave] = s;
    __syncthreads();
    if (threadIdx.x == 0) {
        // min_d = -2*(smax + h_a); loss = 0.005 * sum / 32768
        out[0] = (redb[0] + redb[1] + redb[2] + redb[3])
                 * (-2.0f * 0.005f / 32768.f);
    }
}

extern "C" void kernel_launch(void* const* d_in, const int* in_sizes, int n_in,
                              void* d_out, int out_size, void* d_ws, size_t ws_size,
                              hipStream_t stream) {
    const float* x = (const float*)d_in[0];
    const float* y = (const float*)d_in[1];
    float* out = (float*)d_out;

    float* partials = (float*)d_ws;   // 256 floats, all written each launch

    chamfer_fused<<<dim3(256), dim3(256), 131072, stream>>>(x, y, partials);
    final_reduce<<<dim3(1), dim3(256), 0, stream>>>(partials, out);
}

// Round 4
// 70.192 us; speedup vs baseline: 1.0885x; 1.0885x over previous
//
#include <hip/hip_runtime.h>

#define NPTS 4096

typedef __attribute__((ext_vector_type(8)))  short          bf16x8;
typedef __attribute__((ext_vector_type(8)))  unsigned short u16x8;
typedef __attribute__((ext_vector_type(16))) float          f32x16;

__device__ __forceinline__ unsigned short bf16_rne(float f) {
    unsigned u = __float_as_uint(f);
    u += 0x7FFFu + ((u >> 16) & 1u);
    return (unsigned short)(u >> 16);
}
__device__ __forceinline__ float bf16_f(unsigned short s) {
    return __uint_as_float(((unsigned)s) << 16);
}

// s(i,j) = ah.bh(3) + al.bh(3) + ah.bl(3) + 1*hh + 1*hl   (11 K-slots of 16)
// A slots: [ah0,ah1,ah2, al0,al1,al2, ah0,ah1 | ah2, 1, 1, 0,0,0,0,0]
// B slots: [bh0,bh1,bh2, bh0,bh1,bh2, bl0,bl1 | bl2, hh, hl, 0,0,0,0,0]
// 32x32x16 operand layout: lane l -> point (32u + (l&31)), k-slots 8*(l>>5)..+7.
// C/D map: col=lane&31, row=(reg&3)+8*(reg>>2)+4*(lane>>5). All HW-verified.
// R22 lesson: 128KB LDS -> 1 wave/SIMD exposes MFMA/ds latency (+10us). This
// loop REQUIRES 2 blocks/CU.
// R23: full-j per block at 2 blocks/CU via two 64KB B-half stages.
//      512 blocks = 16 clouds x 32 i-slabs(128 rows), 1 i-tile/wave,
//      128 j-tiles/wave (same per-SIMD totals as verified R21 66.49us).
//      Row-max final in-block -> fold h_a -> 1 float/block. Kernel 2 trivial.

// ---------------- pass 0: MFMA chamfer core ----------------
__global__ __launch_bounds__(256, 2) void chamfer_fused(
    const float* __restrict__ x, const float* __restrict__ y,
    float* __restrict__ partials)
{
    extern __shared__ char smem[];                      // 64 KB dynamic
    unsigned short* sB = (unsigned short*)smem;         // B-half fragments
    float (*buf)[32][33] = (float (*)[32][33])smem;     // aliased in epilogue
    __shared__ float redb[4];

    const int bid   = blockIdx.x;
    const int dirb  = bid >> 5;        // 0..15 (A-cloud id)
    const int islab = bid & 31;        // 0..31 (128-row i-slab)

    const int tid = threadIdx.x;
    const int w   = tid >> 6;          // wave 0..3
    const int l   = tid & 63;
    const int g   = l >> 5;            // k-half
    const int pos = l & 31;            // row/col within tile

    const float* Araw = (dirb < 8) ? x + (size_t)dirb * NPTS * 3
                                   : y + (size_t)(dirb - 8) * NPTS * 3;
    const int bcid = dirb ^ 8;
    const float* Braw = (bcid < 8) ? x + (size_t)bcid * NPTS * 3
                                   : y + (size_t)(bcid - 8) * NPTS * 3;

    // ---- A fragment: 1 i-tile per wave (verified recipe) ----
    const int itile = islab * 4 + w;
    bf16x8 afr;
    {
        const float* ap = Araw + (size_t)(itile * 32 + pos) * 3;
        float c0 = ap[0], c1 = ap[1], c2 = ap[2];
        unsigned short h0 = bf16_rne(c0), h1 = bf16_rne(c1), h2 = bf16_rne(c2);
        unsigned short l0 = bf16_rne(c0 - bf16_f(h0));
        unsigned short l1 = bf16_rne(c1 - bf16_f(h1));
        unsigned short l2 = bf16_rne(c2 - bf16_f(h2));
        const short ONE = (short)0x3F80;
        bf16x8 alo, ahi;
        alo[0]=(short)h0; alo[1]=(short)h1; alo[2]=(short)h2; alo[3]=(short)l0;
        alo[4]=(short)l1; alo[5]=(short)l2; alo[6]=(short)h0; alo[7]=(short)h1;
        ahi[0]=(short)h2; ahi[1]=ONE; ahi[2]=ONE; ahi[3]=0;
        ahi[4]=0; ahi[5]=0; ahi[6]=0; ahi[7]=0;
        #pragma unroll
        for (int e = 0; e < 8; ++e) afr[e] = g ? ahi[e] : alo[e];
    }

    f32x16 zc;
    #pragma unroll
    for (int r = 0; r < 16; ++r) zc[r] = 0.f;

    f32x16 run, p0, p1;
    #pragma unroll
    for (int r = 0; r < 16; ++r) { run[r] = -3.0e38f; p0[r] = -3.0e38f; p1[r] = -3.0e38f; }

    const char* BqBase = (const char*)sB + (size_t)g * 512 + (size_t)pos * 16;

#define STAGE(B0, B1)                                                           \
    {                                                                           \
        f32x16 d0 = __builtin_amdgcn_mfma_f32_32x32x16_bf16(afr, B0, zc, 0, 0, 0); \
        f32x16 d1 = __builtin_amdgcn_mfma_f32_32x32x16_bf16(afr, B1, zc, 0, 0, 0); \
        _Pragma("unroll")                                                       \
        for (int r = 0; r < 16; ++r)                                            \
            run[r] = fmaxf(fmaxf(p0[r], p1[r]), run[r]);                        \
        p0 = d0; p1 = d1;                                                       \
    }

    #pragma unroll 1
    for (int half = 0; half < 2; ++half) {
        if (half) __syncthreads();   // half-0 reads done before overwrite

        // ---- convert B half (2048 points) into LDS ----
        // byte layout: u*1024 + ppos*16 (+512 for hi half), u = 0..63
        #pragma unroll
        for (int k = 0; k < 8; ++k) {
            int p = k * 256 + tid;                       // 0..2047 local
            const float* src = Braw + (size_t)(half * 2048 + p) * 3;
            float c0 = src[0], c1 = src[1], c2 = src[2];
            float h  = -0.5f * (c0 * c0 + c1 * c1 + c2 * c2);
            unsigned short h0 = bf16_rne(c0), h1 = bf16_rne(c1), h2 = bf16_rne(c2);
            unsigned short l0 = bf16_rne(c0 - bf16_f(h0));
            unsigned short l1 = bf16_rne(c1 - bf16_f(h1));
            unsigned short l2 = bf16_rne(c2 - bf16_f(h2));
            unsigned short hh = bf16_rne(h);
            unsigned short hl = bf16_rne(h - bf16_f(hh));
            u16x8 blo, bhi;
            blo[0]=h0; blo[1]=h1; blo[2]=h2; blo[3]=h0; blo[4]=h1; blo[5]=h2; blo[6]=l0; blo[7]=l1;
            bhi[0]=l2; bhi[1]=hh; bhi[2]=hl; bhi[3]=0; bhi[4]=0; bhi[5]=0; bhi[6]=0; bhi[7]=0;
            int u = p >> 5, ppos = p & 31;
            char* dst = (char*)sB + (size_t)u * 1024 + (size_t)ppos * 16;
            *(u16x8*)dst         = blo;
            *(u16x8*)(dst + 512) = bhi;
        }
        __syncthreads();   // B half ready

        bf16x8 cb0 = *(const bf16x8*)(BqBase);
        bf16x8 cb1 = *(const bf16x8*)(BqBase + 1024);
        bf16x8 cb2 = *(const bf16x8*)(BqBase + 2048);
        bf16x8 cb3 = *(const bf16x8*)(BqBase + 3072);

        #pragma unroll 1
        for (int j = 0; j < 64; j += 4) {
            bf16x8 nb0, nb1, nb2, nb3;
            if (j < 60) {                   // wave-uniform scalar branch
                const char* Bn = BqBase + (size_t)(j + 4) * 1024;
                nb0 = *(const bf16x8*)(Bn);
                nb1 = *(const bf16x8*)(Bn + 1024);
                nb2 = *(const bf16x8*)(Bn + 2048);
                nb3 = *(const bf16x8*)(Bn + 3072);
            }
            STAGE(cb0, cb1)
            STAGE(cb2, cb3)
            if (j < 60) { cb0 = nb0; cb1 = nb1; cb2 = nb2; cb3 = nb3; }
        }
        // p0/p1 carry across the half boundary (max is associative)
    }
#undef STAGE

    // drain pipeline
    #pragma unroll
    for (int r = 0; r < 16; ++r)
        run[r] = fmaxf(fmaxf(p0[r], p1[r]), run[r]);

    __syncthreads();   // all sB reads complete -> safe to alias smem as buf

    // ---- epilogue: transpose one 32x32 tile per wave (verified C/D map) ----
    #pragma unroll
    for (int r = 0; r < 16; ++r) {
        int rowin = (r & 3) + 8 * (r >> 2) + 4 * g;
        buf[w][rowin][pos] = run[r];
    }
    __syncthreads();

    // row max: lane l -> row (l&31), col-half (l>>5); then pair-combine
    float m = buf[w][l & 31][(l >> 5) * 16];
    #pragma unroll
    for (int k = 1; k < 16; ++k)
        m = fmaxf(m, buf[w][l & 31][(l >> 5) * 16 + k]);
    m = fmaxf(m, __shfl_xor(m, 32));

    // fold h_a = -0.5*|a|^2 (lanes <32 only; each row appears in 2 lanes)
    float s = 0.f;
    if (l < 32) {
        int row = itile * 32 + l;
        const float* ap = Araw + (size_t)row * 3;
        float a0 = ap[0], a1 = ap[1], a2 = ap[2];
        s = m - 0.5f * (a0 * a0 + a1 * a1 + a2 * a2);
    }

    #pragma unroll
    for (int off = 32; off > 0; off >>= 1)
        s += __shfl_down(s, off);

    if (l == 0) redb[w] = s;
    __syncthreads();
    if (tid == 0)
        partials[bid] = redb[0] + redb[1] + redb[2] + redb[3];
}

// ---------------- pass 1: sum 512 partials, scale, store ----------------
__global__ __launch_bounds__(256) void final_reduce(
    const float* __restrict__ partials, float* __restrict__ out)
{
    float s = partials[threadIdx.x] + partials[threadIdx.x + 256];
    #pragma unroll
    for (int off = 32; off > 0; off >>= 1)
        s += __shfl_down(s, off);

    __shared__ float redb[4];
    const int lane = threadIdx.x & 63, wave = threadIdx.x >> 6;
    if (lane == 0) redb[wave] = s;
    __syncthreads();
    if (threadIdx.x == 0) {
        // min_d = -2*(smax + h_a); loss = 0.005 * sum / 32768
        out[0] = (redb[0] + redb[1] + redb[2] + redb[3])
                 * (-2.0f * 0.005f / 32768.f);
    }
}

extern "C" void kernel_launch(void* const* d_in, const int* in_sizes, int n_in,
                              void* d_out, int out_size, void* d_ws, size_t ws_size,
                              hipStream_t stream) {
    const float* x = (const float*)d_in[0];
    const float* y = (const float*)d_in[1];
    float* out = (float*)d_out;

    float* partials = (float*)d_ws;   // 512 floats, all written each launch

    chamfer_fused<<<dim3(512), dim3(256), 65536, stream>>>(x, y, partials);
    final_reduce<<<dim3(1), dim3(256), 0, stream>>>(partials, out);
}